// Round 3
// baseline (349.265 us; speedup 1.0000x reference)
//
#include <hip/hip_runtime.h>
#include <hip/hip_bf16.h>
#include <cstdint>

using short8   = __attribute__((ext_vector_type(8))) short;
using floatx4  = __attribute__((ext_vector_type(4))) float;
using ushort4v = __attribute__((ext_vector_type(4))) unsigned short;

#define DEVI static __device__ __forceinline__

DEVI unsigned short f2bf(float f) {
    union { float f; unsigned u; } v; v.f = f;
    unsigned r = v.u + 0x7FFFu + ((v.u >> 16) & 1u);
    return (unsigned short)(r >> 16);
}

DEVI unsigned cvtpk_bf16(float lo, float hi) {
    unsigned r;
    asm("v_cvt_pk_bf16_f32 %0, %1, %2" : "=v"(r) : "v"(lo), "v"(hi));
    return r;
}

typedef const __attribute__((address_space(1))) unsigned int gas_uint;
typedef __attribute__((address_space(3))) unsigned int las_uint;

DEVI void gload16(const void* g, void* l) {
    __builtin_amdgcn_global_load_lds((gas_uint*)g, (las_uint*)l, 16, 0, 0);
}

DEVI float gelu_f(float x) {
    float z = 0.7978845608028654f * (x + 0.044715f * x * x * x);
    float e = __expf(2.0f * z);
    float t = 1.0f - 2.0f / (e + 1.0f);   // tanh(z), safe at +-inf
    return 0.5f * x * (1.0f + t);
}

// q pre-scale: 0.125 (1/sqrt(64)) * log2(e) so scores land in exp2 domain
#define QSCALE 0.18033688011112042f

// ---------------- weight cast + transpose: W[K][N] fp32 -> Wt[N][K] bf16 ----
__global__ __launch_bounds__(256)
void transpose_cast(const float* __restrict__ W, unsigned short* __restrict__ Wt,
                    int K, int N)
{
    __shared__ float tile[32][33];
    const int n0 = blockIdx.x * 32, k0 = blockIdx.y * 32;
    const int tx = threadIdx.x & 31, ty = threadIdx.x >> 5;   // ty 0..7
#pragma unroll
    for (int j = 0; j < 4; ++j)
        tile[ty + j * 8][tx] = W[(long)(k0 + ty + j * 8) * N + n0 + tx];
    __syncthreads();
#pragma unroll
    for (int j = 0; j < 4; ++j)
        Wt[(long)(n0 + ty + j * 8) * K + k0 + tx] = f2bf(tile[tx][ty + j * 8]);
}

// ---------------- LayerNorm (row=768) + cast to bf16 ------------------------
__global__ __launch_bounds__(256)
void ln_cast_k(const float* __restrict__ x, const float* __restrict__ g,
               const float* __restrict__ beta, unsigned short* __restrict__ out)
{
    const int row = blockIdx.x;
    const int tid = threadIdx.x;
    const float* xr = x + (long)row * 768;
    float v0 = xr[tid], v1 = xr[tid + 256], v2 = xr[tid + 512];
    float s  = v0 + v1 + v2;
    float sq = v0 * v0 + v1 * v1 + v2 * v2;
#pragma unroll
    for (int m = 1; m < 64; m <<= 1) {
        s  += __shfl_xor(s, m);
        sq += __shfl_xor(sq, m);
    }
    __shared__ float ss[4], ssq[4];
    if ((tid & 63) == 0) { ss[tid >> 6] = s; ssq[tid >> 6] = sq; }
    __syncthreads();
    s  = ss[0] + ss[1] + ss[2] + ss[3];
    sq = ssq[0] + ssq[1] + ssq[2] + ssq[3];
    const float mean = s * (1.0f / 768.0f);
    const float var  = sq * (1.0f / 768.0f) - mean * mean;
    const float rstd = rsqrtf(var + 1e-5f);
    unsigned short* orow = out + (long)row * 768;
    orow[tid]       = f2bf((v0 - mean) * rstd * g[tid]       + beta[tid]);
    orow[tid + 256] = f2bf((v1 - mean) * rstd * g[tid + 256] + beta[tid + 256]);
    orow[tid + 512] = f2bf((v2 - mean) * rstd * g[tid + 512] + beta[tid + 512]);
}

// ---------------- 128x128-tile bf16 MFMA GEMM, templated epilogue -----------
// A [M][K] bf16 row-major, Bt [N][K] bf16 (B transposed), M=8192.
// EPI 0: qkv scatter (+bias) -> ob0=q[B,H,T,D] (pre-scaled by QSCALE),
//        ob1=k[B,H,T,D],
//        ob2=vT[B,H,D,T] with token order scrambled within 32-blocks
//        (pos = 8*((t>>2)&3) + 4*((t>>4)&1) + (t&3)) so attn PV fragments
//        read contiguous 16B. MFMA contracts slot-wise, so applying the same
//        permutation to P-slot packing and V keeps the math identical.
// EPI 1: +bias +resid -> of fp32 [M][N]
// EPI 2: +bias, gelu  -> ob0 bf16 [M][N]
// EPI 3: +bias +resid -> of fp32 [M][N]   (resid may alias of)
template<int EPI>
__global__ __launch_bounds__(256)
void gemm128(const unsigned short* __restrict__ A,
             const unsigned short* __restrict__ Bt,
             const float* __restrict__ bias,
             const float* __restrict__ resid,
             unsigned short* __restrict__ ob0,
             unsigned short* __restrict__ ob1,
             unsigned short* __restrict__ ob2,
             float* __restrict__ of,
             int K, int N)
{
    const int mt = blockIdx.x, nt = blockIdx.y;
    const int tid = threadIdx.x;
    const int w = tid >> 6, lane = tid & 63;
    const int l16 = lane & 15, lq = lane >> 4;
    const int wm = w >> 1, wn = w & 1;

    __shared__ unsigned short As[128 * 64];
    __shared__ unsigned short Bs[128 * 64];

    const floatx4 fzero = {0.f, 0.f, 0.f, 0.f};
    floatx4 acc[4][4];
#pragma unroll
    for (int i = 0; i < 4; ++i)
#pragma unroll
        for (int j = 0; j < 4; ++j) acc[i][j] = fzero;

    const char* Abyte = (const char*)A + (long)mt * 128 * K * 2;
    const char* Bbyte = (const char*)Bt + (long)nt * 128 * K * 2;
    const int KT = K >> 6;

    for (int kt = 0; kt < KT; ++kt) {
        const int kbyte = kt * 128;                    // 64 elems * 2B
#pragma unroll
        for (int r4 = 0; r4 < 4; ++r4) {
            int base = (w * 4 + r4) * 1024;
            int loff = base + lane * 16;
            int row  = loff >> 7;                      // 128B per row
            int scb  = (loff & 127) ^ ((row & 7) << 4);
            gload16(Abyte + (long)row * (K * 2) + kbyte + scb, (char*)As + base);
            gload16(Bbyte + (long)row * (K * 2) + kbyte + scb, (char*)Bs + base);
        }
        __syncthreads();
#pragma unroll
        for (int ks = 0; ks < 2; ++ks) {
            const int kb = ks * 64 + lq * 16;
            short8 af[4], bfr[4];
#pragma unroll
            for (int f = 0; f < 4; ++f) {
                int ar = wm * 64 + f * 16 + l16;
                af[f]  = *(const short8*)((const char*)As + ar * 128 + (kb ^ ((ar & 7) << 4)));
                int br = wn * 64 + f * 16 + l16;
                bfr[f] = *(const short8*)((const char*)Bs + br * 128 + (kb ^ ((br & 7) << 4)));
            }
#pragma unroll
            for (int i = 0; i < 4; ++i)
#pragma unroll
                for (int j = 0; j < 4; ++j)
                    acc[i][j] = __builtin_amdgcn_mfma_f32_16x16x32_bf16(af[i], bfr[j], acc[i][j], 0, 0, 0);
        }
        __syncthreads();
    }

    const int col0 = nt * 128 + wn * 64;
    const int row0 = mt * 128 + wm * 64;
#pragma unroll
    for (int j = 0; j < 4; ++j) {
        const int col = col0 + j * 16 + l16;
        const float bv = bias[col];
#pragma unroll
        for (int i = 0; i < 4; ++i) {
            const int rowb = row0 + i * 16 + lq * 4;   // 4 consecutive rows
            float v[4];
#pragma unroll
            for (int r = 0; r < 4; ++r) v[r] = acc[i][j][r] + bv;

            if (EPI == 0) {
                const int which = (col >= 1536) ? 2 : (col >= 768 ? 1 : 0);
                const int c = col - which * 768;
                const int hh = c >> 6, d = c & 63;
                const int bb = rowb >> 11;
                const int t  = rowb & 2047;
                if (which == 2) {
                    ushort4v pk;
#pragma unroll
                    for (int r = 0; r < 4; ++r) pk[r] = f2bf(v[r]);
                    const int tlo = t & 31;   // multiple of 4
                    const int tS  = (t & ~31) + ((tlo & 12) << 1) + ((tlo & 16) >> 2);
                    long vi = ((long)(bb * 12 + hh) * 64 + d) * 2048 + tS;
                    *(ushort4v*)(ob2 + vi) = pk;
                } else {
                    unsigned short* dst = (which == 0) ? ob0 : ob1;
                    const float qs = (which == 0) ? QSCALE : 1.0f;
                    long base = ((long)(bb * 12 + hh) * 2048 + t) * 64 + d;
#pragma unroll
                    for (int r = 0; r < 4; ++r) dst[base + (long)r * 64] = f2bf(v[r] * qs);
                }
            } else if (EPI == 1 || EPI == 3) {
#pragma unroll
                for (int r = 0; r < 4; ++r) {
                    long idx = (long)(rowb + r) * N + col;
                    of[idx] = v[r] + resid[idx];
                }
            } else {  // EPI == 2
#pragma unroll
                for (int r = 0; r < 4; ++r) {
                    long idx = (long)(rowb + r) * N + col;
                    ob0[idx] = f2bf(gelu_f(v[r]));
                }
            }
        }
    }
}

// ---------------- flash attention: one staged K/V tile feeds 128 q-rows -----
DEVI void attn_set(const unsigned short* Ks, const unsigned short* Vs,
                   const float* madd, bool usemask,
                   short8 qf0, short8 qf1,
                   floatx4 (&acc)[4], float& m2, float& ls,
                   int l16, int lq)
{
    const floatx4 fzero = {0.f, 0.f, 0.f, 0.f};
    floatx4 st[8];
#pragma unroll
    for (int f = 0; f < 8; ++f) st[f] = fzero;

    __builtin_amdgcn_s_setprio(1);
#pragma unroll
    for (int f = 0; f < 8; ++f) {
        const int kr = f * 16 + l16;
        const int sw = (kr & 7) << 4;
        short8 ka0 = *(const short8*)((const char*)Ks + kr * 128 + ((lq * 16) ^ sw));
        short8 ka1 = *(const short8*)((const char*)Ks + kr * 128 + ((64 + lq * 16) ^ sw));
        st[f] = __builtin_amdgcn_mfma_f32_16x16x32_bf16(ka0, qf0, st[f], 0, 0, 0);
        st[f] = __builtin_amdgcn_mfma_f32_16x16x32_bf16(ka1, qf1, st[f], 0, 0, 0);
    }
    __builtin_amdgcn_s_setprio(0);

    if (usemask) {
#pragma unroll
        for (int f = 0; f < 8; ++f) {
            floatx4 md = *(const floatx4*)((const char*)madd + f * 64 + lq * 16);
            floatx4 t = st[f];
#pragma unroll
            for (int j = 0; j < 4; ++j) t[j] += md[j];
            st[f] = t;
        }
    }

    float rm = -3e38f;
#pragma unroll
    for (int f = 0; f < 8; ++f) {
        rm = fmaxf(rm, fmaxf(fmaxf(st[f][0], st[f][1]), fmaxf(st[f][2], st[f][3])));
    }
    rm = fmaxf(rm, __shfl_xor(rm, 16));
    rm = fmaxf(rm, __shfl_xor(rm, 32));

    if (!__all(rm <= m2 + 8.0f)) {          // defer-max (T13, THR=8 exp2-domain)
        const float mn = fmaxf(m2, rm);
        const float corr = exp2f(m2 - mn);
        m2 = mn;
        ls *= corr;
        const float c0 = __shfl(corr, lq * 4 + 0);
        const float c1 = __shfl(corr, lq * 4 + 1);
        const float c2 = __shfl(corr, lq * 4 + 2);
        const float c3 = __shfl(corr, lq * 4 + 3);
#pragma unroll
        for (int n = 0; n < 4; ++n) {
            floatx4 t = acc[n];
            t[0] *= c0; t[1] *= c1; t[2] *= c2; t[3] *= c3;
            acc[n] = t;
        }
    }

    float rs = 0.f;
#pragma unroll
    for (int f = 0; f < 8; ++f) {
        floatx4 t = st[f];
#pragma unroll
        for (int j = 0; j < 4; ++j) {
            float p = exp2f(t[j] - m2);
            rs += p;
            t[j] = p;
        }
        st[f] = t;
    }
    rs += __shfl_xor(rs, 16);
    rs += __shfl_xor(rs, 32);
    ls += rs;

    __builtin_amdgcn_s_setprio(1);
#pragma unroll
    for (int c = 0; c < 4; ++c) {
        union { unsigned u[4]; short8 s8; } pu;
        pu.u[0] = cvtpk_bf16(st[2 * c][0],     st[2 * c][1]);
        pu.u[1] = cvtpk_bf16(st[2 * c][2],     st[2 * c][3]);
        pu.u[2] = cvtpk_bf16(st[2 * c + 1][0], st[2 * c + 1][1]);
        pu.u[3] = cvtpk_bf16(st[2 * c + 1][2], st[2 * c + 1][3]);
        const int kb2 = c * 64 + lq * 16;
#pragma unroll
        for (int n = 0; n < 4; ++n) {
            const int vr = n * 16 + l16;
            short8 vb = *(const short8*)((const char*)Vs + vr * 256 + (kb2 ^ ((vr & 7) << 4)));
            acc[n] = __builtin_amdgcn_mfma_f32_16x16x32_bf16(pu.s8, vb, acc[n], 0, 0, 0);
        }
    }
    __builtin_amdgcn_s_setprio(0);
}

// q,k: bf16 [B*H, 2048, 64] (q pre-scaled); vt: bf16 [B*H, 64, 2048]
// (32-token scrambled); y: bf16 [B*T, 768]. 128 q-rows per block (2 sets).
__global__ __launch_bounds__(256)
void attn_fwd(const unsigned short* __restrict__ q,
              const unsigned short* __restrict__ k,
              const unsigned short* __restrict__ vt,
              const float* __restrict__ mask,
              unsigned short* __restrict__ y)
{
    const int qt = blockIdx.x;     // 0..15 (128 q rows each)
    const int bh = blockIdx.y;     // 0..47
    const int b = bh / 12, h = bh - b * 12;
    const int tid = threadIdx.x;
    const int w = tid >> 6, lane = tid & 63;
    const int l16 = lane & 15, lq = lane >> 4;

    __shared__ unsigned short Ks[128 * 64];
    __shared__ unsigned short Vs[64 * 128];
    __shared__ float madd[128];
    __shared__ int mq;

    const char* kg = (const char*)(k + (long)bh * 2048 * 64);
    const char* vg = (const char*)(vt + (long)bh * 64 * 2048);

    // Q fragments in registers (B operand of swapped QK^T), both sets
    const unsigned short* qbase = q + ((long)bh * 2048 + qt * 128 + w * 16 + l16) * 64;
    const short8 qfA0 = *(const short8*)(qbase + lq * 8);
    const short8 qfA1 = *(const short8*)(qbase + 32 + lq * 8);
    const short8 qfB0 = *(const short8*)(qbase + 64 * 64 + lq * 8);
    const short8 qfB1 = *(const short8*)(qbase + 64 * 64 + 32 + lq * 8);

    if (tid == 0) mq = 0;
    __syncthreads();
    {
        const float* mrow = mask + (long)b * 2048 + tid * 8;
        int bad = 0;
#pragma unroll
        for (int j = 0; j < 8; ++j) bad |= (mrow[j] != 1.0f);
        if (bad) atomicOr(&mq, 1);
    }
    __syncthreads();
    const bool usemask = (mq != 0);

    const floatx4 fzero = {0.f, 0.f, 0.f, 0.f};
    floatx4 accA[4], accB[4];
#pragma unroll
    for (int n = 0; n < 4; ++n) { accA[n] = fzero; accB[n] = fzero; }
    float m2A = -1e30f, lsA = 0.f, m2B = -1e30f, lsB = 0.f;

    for (int kt = 0; kt < 16; ++kt) {
#pragma unroll
        for (int r4 = 0; r4 < 4; ++r4) {       // stage K tile + V tile (16KB each)
            int base = (w * 4 + r4) * 1024;
            int loff = base + lane * 16;
            int rowK = loff >> 7;
            int scbK = (loff & 127) ^ ((rowK & 7) << 4);
            gload16(kg + (long)(kt * 128 + rowK) * 128 + scbK, (char*)Ks + base);
            int rowV = loff >> 8;
            int scbV = (loff & 255) ^ ((rowV & 7) << 4);
            gload16(vg + (long)rowV * 4096 + kt * 256 + scbV, (char*)Vs + base);
        }
        if (usemask && tid < 128)
            madd[tid] = (1.0f - mask[b * 2048 + kt * 128 + tid]) * (-10000.0f * 1.4426950408889634f);
        __syncthreads();

        attn_set(Ks, Vs, madd, usemask, qfA0, qfA1, accA, m2A, lsA, l16, lq);
        attn_set(Ks, Vs, madd, usemask, qfB0, qfB1, accB, m2B, lsB, l16, lq);

        __syncthreads();
    }

    // epilogue: normalize + store (set A rows qt*128+w*16.., set B +64)
#pragma unroll
    for (int s = 0; s < 2; ++s) {
        const float li = 1.0f / (s == 0 ? lsA : lsB);
        const float li0 = __shfl(li, lq * 4 + 0);
        const float li1 = __shfl(li, lq * 4 + 1);
        const float li2 = __shfl(li, lq * 4 + 2);
        const float li3 = __shfl(li, lq * 4 + 3);
        const float lir[4] = {li0, li1, li2, li3};
        const floatx4* acc = (s == 0) ? accA : accB;
        unsigned short* ybase = y + ((long)(b * 2048 + qt * 128 + s * 64 + w * 16 + lq * 4)) * 768 + h * 64;
#pragma unroll
        for (int r = 0; r < 4; ++r) {
            unsigned short* yrow = ybase + (long)r * 768;
#pragma unroll
            for (int n = 0; n < 4; ++n)
                yrow[n * 16 + l16] = f2bf(acc[n][r] * lir[r]);
        }
    }
}

// ---------------------------------------------------------------------------
extern "C" void kernel_launch(void* const* d_in, const int* in_sizes, int n_in,
                              void* d_out, int out_size, void* d_ws, size_t ws_size,
                              hipStream_t stream)
{
    const float* x     = (const float*)d_in[0];
    const float* amask = (const float*)d_in[1];
    const float* ln1g  = (const float*)d_in[2];
    const float* ln1b  = (const float*)d_in[3];
    const float* ln2g  = (const float*)d_in[4];
    const float* ln2b  = (const float*)d_in[5];
    const float* Wattn = (const float*)d_in[6];
    const float* battn = (const float*)d_in[7];
    const float* Wproj = (const float*)d_in[8];
    const float* bproj = (const float*)d_in[9];
    const float* Wfc   = (const float*)d_in[10];
    const float* bfc   = (const float*)d_in[11];
    const float* Wout  = (const float*)d_in[12];
    const float* bout  = (const float*)d_in[13];
    float* out = (float*)d_out;

    char* ws = (char*)d_ws;
    unsigned short* wt_attn = (unsigned short*)ws;  ws += (long)2304 * 768 * 2;
    unsigned short* wt_proj = (unsigned short*)ws;  ws += (long)768 * 768 * 2;
    unsigned short* wt_fc   = (unsigned short*)ws;  ws += (long)3072 * 768 * 2;
    unsigned short* wt_out  = (unsigned short*)ws;  ws += (long)768 * 3072 * 2;
    unsigned short* hbuf    = (unsigned short*)ws;  ws += (long)8192 * 768 * 2;
    unsigned short* qbuf    = (unsigned short*)ws;  ws += (long)48 * 2048 * 64 * 2;
    unsigned short* kbuf    = (unsigned short*)ws;  ws += (long)48 * 2048 * 64 * 2;
    unsigned short* vtbuf   = (unsigned short*)ws;  ws += (long)48 * 2048 * 64 * 2;
    unsigned short* ybuf    = (unsigned short*)ws;  ws += (long)8192 * 768 * 2;
    unsigned short* hfc     = (unsigned short*)ws;  ws += (long)8192 * 3072 * 2;

    transpose_cast<<<dim3(2304 / 32, 768 / 32), 256, 0, stream>>>(Wattn, wt_attn, 768, 2304);
    transpose_cast<<<dim3(768 / 32, 768 / 32), 256, 0, stream>>>(Wproj, wt_proj, 768, 768);
    transpose_cast<<<dim3(3072 / 32, 768 / 32), 256, 0, stream>>>(Wfc, wt_fc, 768, 3072);
    transpose_cast<<<dim3(768 / 32, 3072 / 32), 256, 0, stream>>>(Wout, wt_out, 3072, 768);

    ln_cast_k<<<8192, 256, 0, stream>>>(x, ln1g, ln1b, hbuf);

    gemm128<0><<<dim3(64, 18), 256, 0, stream>>>(hbuf, wt_attn, battn, nullptr,
                                                 qbuf, kbuf, vtbuf, nullptr, 768, 2304);

    attn_fwd<<<dim3(16, 48), 256, 0, stream>>>(qbuf, kbuf, vtbuf, amask, ybuf);

    gemm128<1><<<dim3(64, 6), 256, 0, stream>>>(ybuf, wt_proj, bproj, x,
                                                nullptr, nullptr, nullptr, out, 768, 768);

    ln_cast_k<<<8192, 256, 0, stream>>>(out, ln2g, ln2b, hbuf);

    gemm128<2><<<dim3(64, 24), 256, 0, stream>>>(hbuf, wt_fc, bfc, nullptr,
                                                 hfc, nullptr, nullptr, nullptr, 768, 3072);

    gemm128<3><<<dim3(64, 6), 256, 0, stream>>>(hfc, wt_out, bout, out,
                                                nullptr, nullptr, nullptr, out, 3072, 768);
}

// Round 5
// 341.339 us; speedup vs baseline: 1.0232x; 1.0232x over previous
//
#include <hip/hip_runtime.h>
#include <hip/hip_bf16.h>
#include <cstdint>

using short8   = __attribute__((ext_vector_type(8))) short;
using floatx4  = __attribute__((ext_vector_type(4))) float;
using ushort4v = __attribute__((ext_vector_type(4))) unsigned short;

#define DEVI static __device__ __forceinline__

DEVI unsigned short f2bf(float f) {
    union { float f; unsigned u; } v; v.f = f;
    unsigned r = v.u + 0x7FFFu + ((v.u >> 16) & 1u);
    return (unsigned short)(r >> 16);
}

DEVI unsigned cvtpk_bf16(float lo, float hi) {
    unsigned r;
    asm("v_cvt_pk_bf16_f32 %0, %1, %2" : "=v"(r) : "v"(lo), "v"(hi));
    return r;
}

typedef const __attribute__((address_space(1))) unsigned int gas_uint;
typedef __attribute__((address_space(3))) unsigned int las_uint;

DEVI void gload16(const void* g, void* l) {
    __builtin_amdgcn_global_load_lds((gas_uint*)g, (las_uint*)l, 16, 0, 0);
}

DEVI float gelu_f(float x) {
    float z = 0.7978845608028654f * (x + 0.044715f * x * x * x);
    float e = __expf(2.0f * z);
    float t = 1.0f - 2.0f / (e + 1.0f);   // tanh(z), safe at +-inf
    return 0.5f * x * (1.0f + t);
}

// q pre-scale: 0.125 (1/sqrt(64)) * log2(e) so scores land in exp2 domain
#define QSCALE 0.18033688011112042f

// ---------------- weight cast + transpose: W[K][N] fp32 -> Wt[N][K] bf16 ----
__global__ __launch_bounds__(256)
void transpose_cast(const float* __restrict__ W, unsigned short* __restrict__ Wt,
                    int K, int N)
{
    __shared__ float tile[32][33];
    const int n0 = blockIdx.x * 32, k0 = blockIdx.y * 32;
    const int tx = threadIdx.x & 31, ty = threadIdx.x >> 5;   // ty 0..7
#pragma unroll
    for (int j = 0; j < 4; ++j)
        tile[ty + j * 8][tx] = W[(long)(k0 + ty + j * 8) * N + n0 + tx];
    __syncthreads();
#pragma unroll
    for (int j = 0; j < 4; ++j)
        Wt[(long)(n0 + ty + j * 8) * K + k0 + tx] = f2bf(tile[tx][ty + j * 8]);
}

// ---------------- LayerNorm (row=768) + cast to bf16 ------------------------
__global__ __launch_bounds__(256)
void ln_cast_k(const float* __restrict__ x, const float* __restrict__ g,
               const float* __restrict__ beta, unsigned short* __restrict__ out)
{
    const int row = blockIdx.x;
    const int tid = threadIdx.x;
    const float* xr = x + (long)row * 768;
    float v0 = xr[tid], v1 = xr[tid + 256], v2 = xr[tid + 512];
    float s  = v0 + v1 + v2;
    float sq = v0 * v0 + v1 * v1 + v2 * v2;
#pragma unroll
    for (int m = 1; m < 64; m <<= 1) {
        s  += __shfl_xor(s, m);
        sq += __shfl_xor(sq, m);
    }
    __shared__ float ss[4], ssq[4];
    if ((tid & 63) == 0) { ss[tid >> 6] = s; ssq[tid >> 6] = sq; }
    __syncthreads();
    s  = ss[0] + ss[1] + ss[2] + ss[3];
    sq = ssq[0] + ssq[1] + ssq[2] + ssq[3];
    const float mean = s * (1.0f / 768.0f);
    const float var  = sq * (1.0f / 768.0f) - mean * mean;
    const float rstd = rsqrtf(var + 1e-5f);
    unsigned short* orow = out + (long)row * 768;
    orow[tid]       = f2bf((v0 - mean) * rstd * g[tid]       + beta[tid]);
    orow[tid + 256] = f2bf((v1 - mean) * rstd * g[tid + 256] + beta[tid + 256]);
    orow[tid + 512] = f2bf((v2 - mean) * rstd * g[tid + 512] + beta[tid + 512]);
}

// ---------------- 128x128-tile bf16 MFMA GEMM, templated epilogue -----------
// A [M][K] bf16 row-major, Bt [N][K] bf16 (B transposed), M=8192.
// EPI 0: qkv scatter (+bias) -> ob0=q[B,H,T,D] (pre-scaled by QSCALE),
//        ob1=k[B,H,T,D],
//        ob2=vT[B,H,D,T] with token order scrambled within 32-blocks
//        (pos = 8*((t>>2)&3) + 4*((t>>4)&1) + (t&3)) so attn PV fragments
//        read contiguous 16B. MFMA contracts slot-wise, so applying the same
//        permutation to P-slot packing and V keeps the math identical.
// EPI 1: +bias +resid -> of fp32 [M][N]
// EPI 2: +bias, gelu  -> ob0 bf16 [M][N]
// EPI 3: +bias +resid -> of fp32 [M][N]   (resid may alias of)
template<int EPI>
__global__ __launch_bounds__(256)
void gemm128(const unsigned short* __restrict__ A,
             const unsigned short* __restrict__ Bt,
             const float* __restrict__ bias,
             const float* __restrict__ resid,
             unsigned short* __restrict__ ob0,
             unsigned short* __restrict__ ob1,
             unsigned short* __restrict__ ob2,
             float* __restrict__ of,
             int K, int N)
{
    const int mt = blockIdx.x, nt = blockIdx.y;
    const int tid = threadIdx.x;
    const int w = tid >> 6, lane = tid & 63;
    const int l16 = lane & 15, lq = lane >> 4;
    const int wm = w >> 1, wn = w & 1;

    __shared__ unsigned short As[128 * 64];
    __shared__ unsigned short Bs[128 * 64];

    const floatx4 fzero = {0.f, 0.f, 0.f, 0.f};
    floatx4 acc[4][4];
#pragma unroll
    for (int i = 0; i < 4; ++i)
#pragma unroll
        for (int j = 0; j < 4; ++j) acc[i][j] = fzero;

    const char* Abyte = (const char*)A + (long)mt * 128 * K * 2;
    const char* Bbyte = (const char*)Bt + (long)nt * 128 * K * 2;
    const int KT = K >> 6;

    for (int kt = 0; kt < KT; ++kt) {
        const int kbyte = kt * 128;                    // 64 elems * 2B
#pragma unroll
        for (int r4 = 0; r4 < 4; ++r4) {
            int base = (w * 4 + r4) * 1024;
            int loff = base + lane * 16;
            int row  = loff >> 7;                      // 128B per row
            int scb  = (loff & 127) ^ ((row & 7) << 4);
            gload16(Abyte + (long)row * (K * 2) + kbyte + scb, (char*)As + base);
            gload16(Bbyte + (long)row * (K * 2) + kbyte + scb, (char*)Bs + base);
        }
        __syncthreads();
#pragma unroll
        for (int ks = 0; ks < 2; ++ks) {
            const int kb = ks * 64 + lq * 16;
            short8 af[4], bfr[4];
#pragma unroll
            for (int f = 0; f < 4; ++f) {
                int ar = wm * 64 + f * 16 + l16;
                af[f]  = *(const short8*)((const char*)As + ar * 128 + (kb ^ ((ar & 7) << 4)));
                int br = wn * 64 + f * 16 + l16;
                bfr[f] = *(const short8*)((const char*)Bs + br * 128 + (kb ^ ((br & 7) << 4)));
            }
#pragma unroll
            for (int i = 0; i < 4; ++i)
#pragma unroll
                for (int j = 0; j < 4; ++j)
                    acc[i][j] = __builtin_amdgcn_mfma_f32_16x16x32_bf16(af[i], bfr[j], acc[i][j], 0, 0, 0);
        }
        __syncthreads();
    }

    const int col0 = nt * 128 + wn * 64;
    const int row0 = mt * 128 + wm * 64;
#pragma unroll
    for (int j = 0; j < 4; ++j) {
        const int col = col0 + j * 16 + l16;
        const float bv = bias[col];
#pragma unroll
        for (int i = 0; i < 4; ++i) {
            const int rowb = row0 + i * 16 + lq * 4;   // 4 consecutive rows
            float v[4];
#pragma unroll
            for (int r = 0; r < 4; ++r) v[r] = acc[i][j][r] + bv;

            if (EPI == 0) {
                const int which = (col >= 1536) ? 2 : (col >= 768 ? 1 : 0);
                const int c = col - which * 768;
                const int hh = c >> 6, d = c & 63;
                const int bb = rowb >> 11;
                const int t  = rowb & 2047;
                if (which == 2) {
                    ushort4v pk;
#pragma unroll
                    for (int r = 0; r < 4; ++r) pk[r] = f2bf(v[r]);
                    const int tlo = t & 31;   // multiple of 4
                    const int tS  = (t & ~31) + ((tlo & 12) << 1) + ((tlo & 16) >> 2);
                    long vi = ((long)(bb * 12 + hh) * 64 + d) * 2048 + tS;
                    *(ushort4v*)(ob2 + vi) = pk;
                } else {
                    unsigned short* dst = (which == 0) ? ob0 : ob1;
                    const float qs = (which == 0) ? QSCALE : 1.0f;
                    long base = ((long)(bb * 12 + hh) * 2048 + t) * 64 + d;
#pragma unroll
                    for (int r = 0; r < 4; ++r) dst[base + (long)r * 64] = f2bf(v[r] * qs);
                }
            } else if (EPI == 1 || EPI == 3) {
#pragma unroll
                for (int r = 0; r < 4; ++r) {
                    long idx = (long)(rowb + r) * N + col;
                    of[idx] = v[r] + resid[idx];
                }
            } else {  // EPI == 2
#pragma unroll
                for (int r = 0; r < 4; ++r) {
                    long idx = (long)(rowb + r) * N + col;
                    ob0[idx] = f2bf(gelu_f(v[r]));
                }
            }
        }
    }
}

// ---------------- flash attention fwd, register-P via swapped QK^T ----------
// q,k: bf16 [B*H, 2048, 64] (q pre-scaled); vt: bf16 [B*H, 64, 2048]
// (32-token scrambled); y: bf16 [B*T, 768]. 64 q-rows per block.
__global__ __launch_bounds__(256)
void attn_fwd(const unsigned short* __restrict__ q,
              const unsigned short* __restrict__ k,
              const unsigned short* __restrict__ vt,
              const float* __restrict__ mask,
              unsigned short* __restrict__ y)
{
    const int qt = blockIdx.x;     // 0..31
    const int bh = blockIdx.y;     // 0..47
    const int b = bh / 12, h = bh - b * 12;
    const int tid = threadIdx.x;
    const int w = tid >> 6, lane = tid & 63;
    const int l16 = lane & 15, lq = lane >> 4;

    __shared__ unsigned short Ks[128 * 64];
    __shared__ unsigned short Vs[64 * 128];
    __shared__ float madd[128];
    __shared__ int mq;

    if (tid == 0) mq = 0;
    __syncthreads();
    {
        const float* mrow = mask + (long)b * 2048 + tid * 8;
        int bad = 0;
#pragma unroll
        for (int j = 0; j < 8; ++j) bad |= (mrow[j] != 1.0f);
        if (bad) atomicOr(&mq, 1);
    }

    // Q fragments in registers (B operand of swapped QK^T)
    const unsigned short* qrow = q + ((long)bh * 2048 + qt * 64 + w * 16 + l16) * 64;
    const short8 qf0 = *(const short8*)(qrow + lq * 8);
    const short8 qf1 = *(const short8*)(qrow + 32 + lq * 8);

    // hoisted per-lane staging offsets (loop-invariant)
    const char* kg = (const char*)(k + (long)bh * 2048 * 64);
    const char* vg = (const char*)(vt + (long)bh * 64 * 2048);
    int koff[4], voff[4], lbase[4];
#pragma unroll
    for (int r4 = 0; r4 < 4; ++r4) {
        int base = (w * 4 + r4) * 1024;
        int loff = base + lane * 16;
        int rowK = loff >> 7;
        koff[r4] = rowK * 128 + ((loff & 127) ^ ((rowK & 7) << 4));
        int rowV = loff >> 8;
        voff[r4] = rowV * 4096 + ((loff & 255) ^ ((rowV & 7) << 4));
        lbase[r4] = base;
    }

    __syncthreads();
    const bool usemask = (mq != 0);

    const floatx4 fzero = {0.f, 0.f, 0.f, 0.f};
    floatx4 accO[4];
#pragma unroll
    for (int n = 0; n < 4; ++n) accO[n] = fzero;
    float m2 = -1e30f, lsum = 0.f;

    for (int kt = 0; kt < 16; ++kt) {
        const char* kgt = kg + (long)kt * 16384;   // 128 rows * 128B
        const char* vgt = vg + kt * 256;           // 128 cols * 2B
#pragma unroll
        for (int r4 = 0; r4 < 4; ++r4) {
            gload16(kgt + koff[r4], (char*)Ks + lbase[r4]);
            gload16(vgt + voff[r4], (char*)Vs + lbase[r4]);
        }
        if (usemask && tid < 128)
            madd[tid] = (1.0f - mask[b * 2048 + kt * 128 + tid]) * (-10000.0f * 1.4426950408889634f);
        __syncthreads();

        // S^T = K Q^T : lane -> S[key=f*16+lq*4+j][q=l16]
        floatx4 st[8];
#pragma unroll
        for (int f = 0; f < 8; ++f) st[f] = fzero;
        __builtin_amdgcn_s_setprio(1);
#pragma unroll
        for (int f = 0; f < 8; ++f) {
            const int kr = f * 16 + l16;
            const int sw = (kr & 7) << 4;
            short8 ka0 = *(const short8*)((const char*)Ks + kr * 128 + ((lq * 16) ^ sw));
            short8 ka1 = *(const short8*)((const char*)Ks + kr * 128 + ((64 + lq * 16) ^ sw));
            st[f] = __builtin_amdgcn_mfma_f32_16x16x32_bf16(ka0, qf0, st[f], 0, 0, 0);
            st[f] = __builtin_amdgcn_mfma_f32_16x16x32_bf16(ka1, qf1, st[f], 0, 0, 0);
        }
        __builtin_amdgcn_s_setprio(0);

        if (usemask) {
#pragma unroll
            for (int f = 0; f < 8; ++f) {
                floatx4 md = *(const floatx4*)((const char*)madd + f * 64 + lq * 16);
                floatx4 t = st[f];
#pragma unroll
                for (int j = 0; j < 4; ++j) t[j] += md[j];
                st[f] = t;
            }
        }

        // row max (32 local values + cross-lq reduce)
        float rm = -3e38f;
#pragma unroll
        for (int f = 0; f < 8; ++f)
            rm = fmaxf(rm, fmaxf(fmaxf(st[f][0], st[f][1]), fmaxf(st[f][2], st[f][3])));
        rm = fmaxf(rm, __shfl_xor(rm, 16));
        rm = fmaxf(rm, __shfl_xor(rm, 32));

        if (!__all(rm <= m2 + 8.0f)) {      // defer-max (T13, THR=8 exp2-domain)
            const float mn = fmaxf(m2, rm);
            const float corr = exp2f(m2 - mn);
            m2 = mn;
            lsum *= corr;
            const float c0 = __shfl(corr, lq * 4 + 0);
            const float c1 = __shfl(corr, lq * 4 + 1);
            const float c2 = __shfl(corr, lq * 4 + 2);
            const float c3 = __shfl(corr, lq * 4 + 3);
#pragma unroll
            for (int n = 0; n < 4; ++n) {
                floatx4 t = accO[n];
                t[0] *= c0; t[1] *= c1; t[2] *= c2; t[3] *= c3;
                accO[n] = t;
            }
        }

        // P = exp2(S - m2) (scalar, proven path); pack to bf16 for PV
        float rs = 0.f;
        unsigned pw[16];
#pragma unroll
        for (int f = 0; f < 8; ++f) {
            const floatx4 t = st[f];
            const float e0 = exp2f(t[0] - m2);
            const float e1 = exp2f(t[1] - m2);
            const float e2 = exp2f(t[2] - m2);
            const float e3 = exp2f(t[3] - m2);
            rs += (e0 + e1) + (e2 + e3);
            pw[f * 2]     = cvtpk_bf16(e0, e1);
            pw[f * 2 + 1] = cvtpk_bf16(e2, e3);
        }
        rs += __shfl_xor(rs, 16);
        rs += __shfl_xor(rs, 32);
        lsum += rs;

        // O += P V  (P packed lane-locally; V tokens pre-scrambled to match)
        __builtin_amdgcn_s_setprio(1);
#pragma unroll
        for (int c = 0; c < 4; ++c) {
            union { unsigned u[4]; short8 s8; } pu;
            pu.u[0] = pw[c * 4 + 0];
            pu.u[1] = pw[c * 4 + 1];
            pu.u[2] = pw[c * 4 + 2];
            pu.u[3] = pw[c * 4 + 3];
            const int kb2 = c * 64 + lq * 16;
#pragma unroll
            for (int n = 0; n < 4; ++n) {
                const int vr = n * 16 + l16;
                short8 vb = *(const short8*)((const char*)Vs + vr * 256 + (kb2 ^ ((vr & 7) << 4)));
                accO[n] = __builtin_amdgcn_mfma_f32_16x16x32_bf16(pu.s8, vb, accO[n], 0, 0, 0);
            }
        }
        __builtin_amdgcn_s_setprio(0);
        __syncthreads();
    }

    const float li = 1.0f / lsum;
    const float li0 = __shfl(li, lq * 4 + 0);
    const float li1 = __shfl(li, lq * 4 + 1);
    const float li2 = __shfl(li, lq * 4 + 2);
    const float li3 = __shfl(li, lq * 4 + 3);
    const float lir[4] = {li0, li1, li2, li3};
    unsigned short* ybase = y + ((long)(b * 2048 + qt * 64 + w * 16 + lq * 4)) * 768 + h * 64;
#pragma unroll
    for (int r = 0; r < 4; ++r) {
        unsigned short* yrow = ybase + (long)r * 768;
#pragma unroll
        for (int n = 0; n < 4; ++n)
            yrow[n * 16 + l16] = f2bf(accO[n][r] * lir[r]);
    }
}

// ---------------------------------------------------------------------------
extern "C" void kernel_launch(void* const* d_in, const int* in_sizes, int n_in,
                              void* d_out, int out_size, void* d_ws, size_t ws_size,
                              hipStream_t stream)
{
    const float* x     = (const float*)d_in[0];
    const float* amask = (const float*)d_in[1];
    const float* ln1g  = (const float*)d_in[2];
    const float* ln1b  = (const float*)d_in[3];
    const float* ln2g  = (const float*)d_in[4];
    const float* ln2b  = (const float*)d_in[5];
    const float* Wattn = (const float*)d_in[6];
    const float* battn = (const float*)d_in[7];
    const float* Wproj = (const float*)d_in[8];
    const float* bproj = (const float*)d_in[9];
    const float* Wfc   = (const float*)d_in[10];
    const float* bfc   = (const float*)d_in[11];
    const float* Wout  = (const float*)d_in[12];
    const float* bout  = (const float*)d_in[13];
    float* out = (float*)d_out;

    char* ws = (char*)d_ws;
    unsigned short* wt_attn = (unsigned short*)ws;  ws += (long)2304 * 768 * 2;
    unsigned short* wt_proj = (unsigned short*)ws;  ws += (long)768 * 768 * 2;
    unsigned short* wt_fc   = (unsigned short*)ws;  ws += (long)3072 * 768 * 2;
    unsigned short* wt_out  = (unsigned short*)ws;  ws += (long)768 * 3072 * 2;
    unsigned short* hbuf    = (unsigned short*)ws;  ws += (long)8192 * 768 * 2;
    unsigned short* qbuf    = (unsigned short*)ws;  ws += (long)48 * 2048 * 64 * 2;
    unsigned short* kbuf    = (unsigned short*)ws;  ws += (long)48 * 2048 * 64 * 2;
    unsigned short* vtbuf   = (unsigned short*)ws;  ws += (long)48 * 2048 * 64 * 2;
    unsigned short* ybuf    = (unsigned short*)ws;  ws += (long)8192 * 768 * 2;
    unsigned short* hfc     = (unsigned short*)ws;  ws += (long)8192 * 3072 * 2;

    transpose_cast<<<dim3(2304 / 32, 768 / 32), 256, 0, stream>>>(Wattn, wt_attn, 768, 2304);
    transpose_cast<<<dim3(768 / 32, 768 / 32), 256, 0, stream>>>(Wproj, wt_proj, 768, 768);
    transpose_cast<<<dim3(3072 / 32, 768 / 32), 256, 0, stream>>>(Wfc, wt_fc, 768, 3072);
    transpose_cast<<<dim3(768 / 32, 3072 / 32), 256, 0, stream>>>(Wout, wt_out, 3072, 768);

    ln_cast_k<<<8192, 256, 0, stream>>>(x, ln1g, ln1b, hbuf);

    gemm128<0><<<dim3(64, 18), 256, 0, stream>>>(hbuf, wt_attn, battn, nullptr,
                                                 qbuf, kbuf, vtbuf, nullptr, 768, 2304);

    attn_fwd<<<dim3(32, 48), 256, 0, stream>>>(qbuf, kbuf, vtbuf, amask, ybuf);

    gemm128<1><<<dim3(64, 6), 256, 0, stream>>>(ybuf, wt_proj, bproj, x,
                                                nullptr, nullptr, nullptr, out, 768, 768);

    ln_cast_k<<<8192, 256, 0, stream>>>(out, ln2g, ln2b, hbuf);

    gemm128<2><<<dim3(64, 24), 256, 0, stream>>>(hbuf, wt_fc, bfc, nullptr,
                                                 hfc, nullptr, nullptr, nullptr, 768, 3072);

    gemm128<3><<<dim3(64, 6), 256, 0, stream>>>(hfc, wt_out, bout, out,
                                                nullptr, nullptr, nullptr, out, 3072, 768);
}